// Round 11
// baseline (705.590 us; speedup 1.0000x reference)
//
#include <hip/hip_runtime.h>
#include <hip/hip_cooperative_groups.h>

namespace cg = cooperative_groups;

#define NN 50000
#define NE 800000
#define DD 128
#define BSH 6
#define BSZ 64                                // nodes per bucket
#define NBUCK ((NN + BSZ - 1) / BSZ)          // 782
#define GB 1024                               // grid blocks (4/CU, co-resident)
#define TPB 256
#define EPB ((NE + GB - 1) / GB)              // 782 edges per block
#define NWAVES (GB * TPB / 64)                // 4096
#define CHUNKN ((NN + NWAVES - 1) / NWAVES)   // 13 nodes per wave in gather

__device__ __forceinline__ unsigned short f2bf(float x) {
    unsigned u = __float_as_uint(x);
    unsigned r = u + 0x7FFF + ((u >> 16) & 1);   // round-to-nearest-even
    return (unsigned short)(r >> 16);
}
__device__ __forceinline__ float bf2f(unsigned short x) {
    return __uint_as_float((unsigned)x << 16);
}

__global__ void __launch_bounds__(TPB) mega_kernel(
        const int* __restrict__ feat, const int* __restrict__ src,
        const int* __restrict__ dst, const float* __restrict__ emb,
        const float* __restrict__ bias, float* __restrict__ out,
        int* __restrict__ histD, int* __restrict__ histS,
        int* __restrict__ SD, int* __restrict__ SS,
        int* __restrict__ baseD, int* __restrict__ baseS,
        int* __restrict__ baseN, int* __restrict__ cntN,
        unsigned int* __restrict__ sortedD, unsigned char* __restrict__ sortedS,
        unsigned short* __restrict__ srcfine, ushort4* __restrict__ h4) {
    cg::grid_group grid = cg::this_grid();
    __shared__ int lds[2 * NBUCK];
    int t = threadIdx.x, blk = blockIdx.x;
    int ebeg = blk * EPB, eend = min(ebeg + EPB, NE);

    // ---- Phase 1: per-block LDS histograms of dst>>6 and src>>6
    {
        int* hD = lds;
        int* hS = lds + NBUCK;
        for (int b = t; b < NBUCK; b += TPB) { hD[b] = 0; hS[b] = 0; }
        __syncthreads();
        for (int i = ebeg + t; i < eend; i += TPB) {
            atomicAdd(&hD[dst[i] >> BSH], 1);
            atomicAdd(&hS[src[i] >> BSH], 1);
        }
        __syncthreads();
        for (int b = t; b < NBUCK; b += TPB) {
            histD[b * GB + blk] = hD[b];
            histS[b * GB + blk] = hS[b];
        }
    }
    grid.sync();

    // ---- Phase 2: within-bin exclusive scan over GB entries (int4 vectorized)
    for (int task = blk; task < 2 * NBUCK; task += GB) {
        int* hist = (task < NBUCK) ? histD : histS;
        int* S = (task < NBUCK) ? SD : SS;
        int bin = (task < NBUCK) ? task : task - NBUCK;
        int4 e = ((int4*)(hist + (size_t)bin * GB))[t];
        int s = e.x + e.y + e.z + e.w;
        lds[t] = s;
        __syncthreads();
        for (int off = 1; off < TPB; off <<= 1) {
            int x = (t >= off) ? lds[t - off] : 0;
            __syncthreads();
            lds[t] += x;
            __syncthreads();
        }
        int excl = lds[t] - s;
        int4 w;
        w.x = excl;
        w.y = excl + e.x;
        w.z = excl + e.x + e.y;
        w.w = excl + e.x + e.y + e.z;
        ((int4*)(hist + (size_t)bin * GB))[t] = w;
        if (t == TPB - 1) S[bin] = excl + s;   // bin total
        __syncthreads();
    }
    grid.sync();

    // ---- Phase 3: cross-bin exclusive scan (block 0 -> D, block 1 -> S)
    if (blk < 2) {
        const int* S = blk ? SS : SD;
        int* base = blk ? baseS : baseD;
        int e[4], s = 0;
        for (int k = 0; k < 4; k++) {
            int i = 4 * t + k;
            e[k] = (i < NBUCK) ? S[i] : 0;
            s += e[k];
        }
        lds[t] = s;
        __syncthreads();
        for (int off = 1; off < TPB; off <<= 1) {
            int x = (t >= off) ? lds[t - off] : 0;
            __syncthreads();
            lds[t] += x;
            __syncthreads();
        }
        int excl = lds[t] - s;
        for (int k = 0; k < 4; k++) {
            int i = 4 * t + k;
            if (i < NBUCK) base[i] = excl;
            excl += e[k];
        }
    }
    grid.sync();

    // ---- Phase 4: scatter into dst-buckets (src|lo<<16) and src-buckets (lo byte)
    {
        int* curD = lds;
        int* curS = lds + NBUCK;
        for (int b = t; b < NBUCK; b += TPB) {
            curD[b] = baseD[b] + histD[b * GB + blk];
            curS[b] = baseS[b] + histS[b * GB + blk];
        }
        __syncthreads();
        for (int i = ebeg + t; i < eend; i += TPB) {
            int sv = src[i], dv = dst[i];
            int pD = atomicAdd(&curD[dv >> BSH], 1);
            sortedD[pD] = (unsigned)sv | ((unsigned)(dv & (BSZ - 1)) << 16);
            int pS = atomicAdd(&curS[sv >> BSH], 1);
            sortedS[pS] = (unsigned char)(sv & (BSZ - 1));
        }
    }
    grid.sync();

    // ---- Phase 5: finesort (dst-buckets) / hbuild (src-buckets)
    for (int task = blk; task < 2 * NBUCK; task += GB) {
        int* lh = lds;
        int* lcur = lds + BSZ;
        if (task < NBUCK) {
            int bin = task;
            int bbeg = baseD[bin];
            int bend = (bin == NBUCK - 1) ? NE : baseD[bin + 1];
            if (t < BSZ) lh[t] = 0;
            __syncthreads();
            for (int i = bbeg + t; i < bend; i += TPB) atomicAdd(&lh[sortedD[i] >> 16], 1);
            __syncthreads();
            if (t < BSZ) {                 // wave 0: shfl exclusive scan of 64
                int v = lh[t];
                int x = v;
                for (int off = 1; off < 64; off <<= 1) {
                    int y = __shfl_up(x, off);
                    if (t >= off) x += y;
                }
                int excl = bbeg + x - v;
                lcur[t] = excl;
                int n = (bin << BSH) + t;
                if (n < NN) { baseN[n] = excl; cntN[n] = v; }
            }
            __syncthreads();
            for (int i = bbeg + t; i < bend; i += TPB) {
                unsigned e = sortedD[i];
                int pos = atomicAdd(&lcur[e >> 16], 1);
                srcfine[pos] = (unsigned short)(e & 0xFFFF);
            }
            __syncthreads();
        } else {
            int bin = task - NBUCK;
            int bbeg = baseS[bin];
            int bend = (bin == NBUCK - 1) ? NE : baseS[bin + 1];
            if (t < BSZ) lh[t] = 0;
            __syncthreads();
            for (int i = bbeg + t; i < bend; i += TPB) atomicAdd(&lh[sortedS[i]], 1);
            __syncthreads();
            int w = t >> 6, lane = t & 63;
            int half = lane >> 5, sl = lane & 31;
            for (int k = 0; k < 8; k++) {
                int lo = (w << 4) + (k << 1) + half;
                int n = (bin << BSH) + lo;
                if (n < NN) {
                    float nl = rsqrtf((float)max(lh[lo], 1));
                    int f = feat[n];
                    float4 v = ((const float4*)(emb + (size_t)f * DD))[sl];
                    h4[(size_t)n * 32 + sl] = make_ushort4(f2bf(v.x * nl), f2bf(v.y * nl),
                                                           f2bf(v.z * nl), f2bf(v.w * nl));
                }
            }
            __syncthreads();
        }
    }
    grid.sync();

    // ---- Phase 6: gather — persistent waves, half-wave ushort4 MLP body
    {
        int gwid = (blk * TPB + t) >> 6;
        int lane = t & 63;
        int half = lane >> 5, sl = lane & 31;
        float4 bi = ((const float4*)bias)[sl];
        int nbeg = gwid * CHUNKN, nend = min(nbeg + CHUNKN, NN);
        for (int wid = nbeg; wid < nend; wid++) {
            int cnt = cntN[wid];
            int beg = baseN[wid];
            float a0 = 0.f, a1 = 0.f, a2 = 0.f, a3 = 0.f;
            for (int b0 = 0; b0 < cnt; b0 += 64) {
                int m = min(cnt - b0, 64);
                int idx = (lane < m) ? (int)srcfine[beg + b0 + lane] : 0;
                int j = 0;
                for (; j + 7 < m; j += 8) {
                    int s0 = __shfl(idx, j + half);
                    int s1 = __shfl(idx, j + 2 + half);
                    int s2 = __shfl(idx, j + 4 + half);
                    int s3 = __shfl(idx, j + 6 + half);
                    ushort4 v0 = h4[(size_t)s0 * 32 + sl];
                    ushort4 v1 = h4[(size_t)s1 * 32 + sl];
                    ushort4 v2 = h4[(size_t)s2 * 32 + sl];
                    ushort4 v3 = h4[(size_t)s3 * 32 + sl];
                    a0 += bf2f(v0.x) + bf2f(v1.x) + bf2f(v2.x) + bf2f(v3.x);
                    a1 += bf2f(v0.y) + bf2f(v1.y) + bf2f(v2.y) + bf2f(v3.y);
                    a2 += bf2f(v0.z) + bf2f(v1.z) + bf2f(v2.z) + bf2f(v3.z);
                    a3 += bf2f(v0.w) + bf2f(v1.w) + bf2f(v2.w) + bf2f(v3.w);
                }
                for (; j + 1 < m; j += 2) {
                    int s0 = __shfl(idx, j + half);
                    ushort4 v0 = h4[(size_t)s0 * 32 + sl];
                    a0 += bf2f(v0.x);
                    a1 += bf2f(v0.y);
                    a2 += bf2f(v0.z);
                    a3 += bf2f(v0.w);
                }
                if (j < m) {                 // odd leftover: half 0 only
                    int s0 = __shfl(idx, j);
                    if (half == 0) {
                        ushort4 v0 = h4[(size_t)s0 * 32 + sl];
                        a0 += bf2f(v0.x);
                        a1 += bf2f(v0.y);
                        a2 += bf2f(v0.z);
                        a3 += bf2f(v0.w);
                    }
                }
            }
            a0 += __shfl_xor(a0, 32);
            a1 += __shfl_xor(a1, 32);
            a2 += __shfl_xor(a2, 32);
            a3 += __shfl_xor(a3, 32);
            if (half == 0) {
                float nr = rsqrtf((float)max(cnt, 1));
                ((float4*)(out + (size_t)wid * DD))[sl] =
                    make_float4(a0 * nr + bi.x, a1 * nr + bi.y, a2 * nr + bi.z, a3 * nr + bi.w);
            }
        }
    }
}

extern "C" void kernel_launch(void* const* d_in, const int* in_sizes, int n_in,
                              void* d_out, int out_size, void* d_ws, size_t ws_size,
                              hipStream_t stream) {
    const int* feat = (const int*)d_in[0];
    const int* src  = (const int*)d_in[1];
    const int* dst  = (const int*)d_in[2];
    const float* emb  = (const float*)d_in[3];
    const float* bias = (const float*)d_in[4];
    float* out = (float*)d_out;

    // Workspace layout (~25 MB)
    int* histD = (int*)d_ws;                          // NBUCK*GB (3.2 MB)
    int* histS = histD + (size_t)NBUCK * GB;          // NBUCK*GB
    int* SD    = histS + (size_t)NBUCK * GB;          // 800 (padded)
    int* SS    = SD + 800;
    int* baseD = SS + 800;
    int* baseS = baseD + 800;
    int* baseN = baseS + 800;                         // NN
    int* cntN  = baseN + NN;                          // NN
    unsigned int* sortedD = (unsigned int*)(cntN + NN);              // NE
    ushort4* h4 = (ushort4*)(sortedD + NE);           // NN*32 ushort4 (12.8 MB, 16B-aligned)
    unsigned short* srcfine = (unsigned short*)(h4 + (size_t)NN * 32); // NE ushort
    unsigned char* sortedS = (unsigned char*)(srcfine + NE);         // NE bytes

    void* args[] = {
        (void*)&feat, (void*)&src, (void*)&dst, (void*)&emb, (void*)&bias, (void*)&out,
        (void*)&histD, (void*)&histS, (void*)&SD, (void*)&SS, (void*)&baseD, (void*)&baseS,
        (void*)&baseN, (void*)&cntN, (void*)&sortedD, (void*)&sortedS,
        (void*)&srcfine, (void*)&h4
    };
    hipLaunchCooperativeKernel((void*)mega_kernel, dim3(GB), dim3(TPB), args, 0, stream);
}

// Round 12
// 85.492 us; speedup vs baseline: 8.2533x; 8.2533x over previous
//
#include <hip/hip_runtime.h>

#define NN 50000
#define NE 800000
#define DD 128
#define BSH 6
#define BSZ 64                                // nodes per bucket
#define NBUCK ((NN + BSZ - 1) / BSZ)          // 782
#define NBLKP 512                             // edge-partition blocks
#define EPB ((NE + NBLKP - 1) / NBLKP)        // 1563
#define TPB 256

__device__ __forceinline__ unsigned short f2bf(float x) {
    unsigned u = __float_as_uint(x);
    unsigned r = u + 0x7FFF + ((u >> 16) & 1);   // round-to-nearest-even
    return (unsigned short)(r >> 16);
}
__device__ __forceinline__ float bf2f(unsigned short x) {
    return __uint_as_float((unsigned)x << 16);
}

// K1: per-block LDS histograms of dst>>6 and src>>6 (no global atomics)
__global__ void hist_kernel(const int* __restrict__ src, const int* __restrict__ dst,
                            int* __restrict__ histD, int* __restrict__ histS) {
    __shared__ int hD[NBUCK], hS[NBUCK];
    int t = threadIdx.x, blk = blockIdx.x;
    for (int b = t; b < NBUCK; b += TPB) { hD[b] = 0; hS[b] = 0; }
    __syncthreads();
    int beg = blk * EPB, end = min(beg + EPB, NE);
    for (int i = beg + t; i < end; i += TPB) {
        atomicAdd(&hD[dst[i] >> BSH], 1);
        atomicAdd(&hS[src[i] >> BSH], 1);
    }
    __syncthreads();
    for (int b = t; b < NBUCK; b += TPB) {
        histD[b * NBLKP + blk] = hD[b];
        histS[b * NBLKP + blk] = hS[b];
    }
}

// K2: within-bin exclusive scan over the 512 block-entries (int2, in place) + bin total.
__global__ void within_kernel(int* __restrict__ histD, int* __restrict__ histS,
                              int* __restrict__ SD, int* __restrict__ SS) {
    __shared__ int col[TPB];
    int t = threadIdx.x, b = blockIdx.x;
    int* hist = (b < NBUCK) ? histD : histS;
    int* S = (b < NBUCK) ? SD : SS;
    int bin = (b < NBUCK) ? b : b - NBUCK;
    int2 e = ((int2*)(hist + (size_t)bin * NBLKP))[t];
    int s = e.x + e.y;
    col[t] = s;
    __syncthreads();
    for (int off = 1; off < TPB; off <<= 1) {
        int x = (t >= off) ? col[t - off] : 0;
        __syncthreads();
        col[t] += x;
        __syncthreads();
    }
    int excl = col[t] - s;
    ((int2*)(hist + (size_t)bin * NBLKP))[t] = make_int2(excl, excl + e.x);
    if (t == TPB - 1) S[bin] = excl + s;        // bin total
}

// K3: scatter with fused cross-bin scan. Each block scans the 782 bin totals in LDS
// (redundant, parallel), block 0 publishes baseD/baseS, cursors seeded base+offs.
__global__ void scatter_kernel(const int* __restrict__ src, const int* __restrict__ dst,
                               const int* __restrict__ offsD, const int* __restrict__ offsS,
                               const int* __restrict__ SD, const int* __restrict__ SS,
                               int* __restrict__ baseD, int* __restrict__ baseS,
                               unsigned int* __restrict__ sortedD,
                               unsigned char* __restrict__ sortedS) {
    __shared__ int curD[NBUCK], curS[NBUCK], scr[TPB];
    int t = threadIdx.x, blk = blockIdx.x;
    // exclusive scan of SD -> curD
    {
        int e[4], s = 0;
        for (int k = 0; k < 4; k++) {
            int i = 4 * t + k;
            e[k] = (i < NBUCK) ? SD[i] : 0;
            s += e[k];
        }
        scr[t] = s;
        __syncthreads();
        for (int off = 1; off < TPB; off <<= 1) {
            int x = (t >= off) ? scr[t - off] : 0;
            __syncthreads();
            scr[t] += x;
            __syncthreads();
        }
        int excl = scr[t] - s;
        for (int k = 0; k < 4; k++) {
            int i = 4 * t + k;
            if (i < NBUCK) curD[i] = excl;
            excl += e[k];
        }
    }
    __syncthreads();
    // exclusive scan of SS -> curS
    {
        int e[4], s = 0;
        for (int k = 0; k < 4; k++) {
            int i = 4 * t + k;
            e[k] = (i < NBUCK) ? SS[i] : 0;
            s += e[k];
        }
        scr[t] = s;
        __syncthreads();
        for (int off = 1; off < TPB; off <<= 1) {
            int x = (t >= off) ? scr[t - off] : 0;
            __syncthreads();
            scr[t] += x;
            __syncthreads();
        }
        int excl = scr[t] - s;
        for (int k = 0; k < 4; k++) {
            int i = 4 * t + k;
            if (i < NBUCK) curS[i] = excl;
            excl += e[k];
        }
    }
    __syncthreads();
    if (blk == 0) {
        for (int b = t; b < NBUCK; b += TPB) { baseD[b] = curD[b]; baseS[b] = curS[b]; }
    }
    for (int b = t; b < NBUCK; b += TPB) {
        curD[b] += offsD[b * NBLKP + blk];
        curS[b] += offsS[b * NBLKP + blk];
    }
    __syncthreads();
    int beg = blk * EPB, end = min(beg + EPB, NE);
    for (int i = beg + t; i < end; i += TPB) {
        int sv = src[i], dv = dst[i];
        int pD = atomicAdd(&curD[dv >> BSH], 1);
        sortedD[pD] = (unsigned)sv | ((unsigned)(dv & (BSZ - 1)) << 16);
        int pS = atomicAdd(&curS[sv >> BSH], 1);
        sortedS[pS] = (unsigned char)(sv & (BSZ - 1));
    }
}

// K4 fused: blocks [0,NBUCK) = finesort of dst-bucket; [NBUCK,2*NBUCK) = hbuild of
// src-bucket (half-wave float4 emb reads, ushort4 h writes).
__global__ void finehb_kernel(const unsigned int* __restrict__ sortedD,
                              const unsigned char* __restrict__ sortedS,
                              const int* __restrict__ baseD, const int* __restrict__ baseS,
                              const int* __restrict__ feat, const float* __restrict__ emb,
                              int* __restrict__ baseN, int* __restrict__ cntN,
                              unsigned short* __restrict__ srcfine,
                              ushort4* __restrict__ h4) {
    __shared__ int lh[BSZ], lcur[BSZ];
    int t = threadIdx.x;
    if (blockIdx.x < NBUCK) {
        int bin = blockIdx.x;
        int beg = baseD[bin];
        int end = (bin == NBUCK - 1) ? NE : baseD[bin + 1];
        if (t < BSZ) lh[t] = 0;
        __syncthreads();
        for (int i = beg + t; i < end; i += TPB) atomicAdd(&lh[sortedD[i] >> 16], 1);
        __syncthreads();
        if (t < BSZ) {                     // wave 0: shfl exclusive scan of 64
            int v = lh[t];
            int x = v;
            for (int off = 1; off < 64; off <<= 1) {
                int y = __shfl_up(x, off);
                if (t >= off) x += y;
            }
            int excl = beg + x - v;
            lcur[t] = excl;
            int n = (bin << BSH) + t;
            if (n < NN) { baseN[n] = excl; cntN[n] = v; }
        }
        __syncthreads();
        for (int i = beg + t; i < end; i += TPB) {
            unsigned e = sortedD[i];
            int pos = atomicAdd(&lcur[e >> 16], 1);
            srcfine[pos] = (unsigned short)(e & 0xFFFF);
        }
    } else {
        int bin = blockIdx.x - NBUCK;
        int beg = baseS[bin];
        int end = (bin == NBUCK - 1) ? NE : baseS[bin + 1];
        if (t < BSZ) lh[t] = 0;
        __syncthreads();
        for (int i = beg + t; i < end; i += TPB) atomicAdd(&lh[sortedS[i]], 1);
        __syncthreads();
        int w = t >> 6, lane = t & 63;
        int half = lane >> 5, sl = lane & 31;
        for (int k = 0; k < 8; k++) {
            int lo = (w << 4) + (k << 1) + half;   // wave w owns 16 consecutive nodes
            int n = (bin << BSH) + lo;
            if (n < NN) {
                float nl = rsqrtf((float)max(lh[lo], 1));
                int f = feat[n];
                float4 v = ((const float4*)(emb + (size_t)f * DD))[sl];
                h4[(size_t)n * 32 + sl] =
                    make_ushort4(f2bf(v.x * nl), f2bf(v.y * nl), f2bf(v.z * nl), f2bf(v.w * nl));
            }
        }
    }
}

// K5: one wave per dst node, two half-waves fetch different edges' 256B h-rows via
// ushort4; 8 edges/iter, 4 independent loads/lane; cross-half shfl_xor reduce.
__global__ void gatherA_kernel(const unsigned short* __restrict__ srcfine,
                               const int* __restrict__ baseN, const int* __restrict__ cntN,
                               const ushort4* __restrict__ h4, const float* __restrict__ bias,
                               float* __restrict__ out) {
    int wid = (blockIdx.x * blockDim.x + threadIdx.x) >> 6;
    int lane = threadIdx.x & 63;
    if (wid >= NN) return;
    int half = lane >> 5, sl = lane & 31;
    int cnt = cntN[wid];
    int beg = baseN[wid];
    float a0 = 0.f, a1 = 0.f, a2 = 0.f, a3 = 0.f;
    for (int b0 = 0; b0 < cnt; b0 += 64) {
        int m = min(cnt - b0, 64);
        int idx = (lane < m) ? (int)srcfine[beg + b0 + lane] : 0;
        int j = 0;
        for (; j + 7 < m; j += 8) {
            int s0 = __shfl(idx, j + half);
            int s1 = __shfl(idx, j + 2 + half);
            int s2 = __shfl(idx, j + 4 + half);
            int s3 = __shfl(idx, j + 6 + half);
            ushort4 v0 = h4[(size_t)s0 * 32 + sl];
            ushort4 v1 = h4[(size_t)s1 * 32 + sl];
            ushort4 v2 = h4[(size_t)s2 * 32 + sl];
            ushort4 v3 = h4[(size_t)s3 * 32 + sl];
            a0 += bf2f(v0.x) + bf2f(v1.x) + bf2f(v2.x) + bf2f(v3.x);
            a1 += bf2f(v0.y) + bf2f(v1.y) + bf2f(v2.y) + bf2f(v3.y);
            a2 += bf2f(v0.z) + bf2f(v1.z) + bf2f(v2.z) + bf2f(v3.z);
            a3 += bf2f(v0.w) + bf2f(v1.w) + bf2f(v2.w) + bf2f(v3.w);
        }
        for (; j + 1 < m; j += 2) {
            int s0 = __shfl(idx, j + half);
            ushort4 v0 = h4[(size_t)s0 * 32 + sl];
            a0 += bf2f(v0.x);
            a1 += bf2f(v0.y);
            a2 += bf2f(v0.z);
            a3 += bf2f(v0.w);
        }
        if (j < m) {                        // odd leftover: half 0 only
            int s0 = __shfl(idx, j);
            if (half == 0) {
                ushort4 v0 = h4[(size_t)s0 * 32 + sl];
                a0 += bf2f(v0.x);
                a1 += bf2f(v0.y);
                a2 += bf2f(v0.z);
                a3 += bf2f(v0.w);
            }
        }
    }
    a0 += __shfl_xor(a0, 32);
    a1 += __shfl_xor(a1, 32);
    a2 += __shfl_xor(a2, 32);
    a3 += __shfl_xor(a3, 32);
    if (half == 0) {
        float nr = rsqrtf((float)max(cnt, 1));
        float4 bi = ((const float4*)bias)[sl];
        ((float4*)(out + (size_t)wid * DD))[sl] =
            make_float4(a0 * nr + bi.x, a1 * nr + bi.y, a2 * nr + bi.z, a3 * nr + bi.w);
    }
}

extern "C" void kernel_launch(void* const* d_in, const int* in_sizes, int n_in,
                              void* d_out, int out_size, void* d_ws, size_t ws_size,
                              hipStream_t stream) {
    const int* feat = (const int*)d_in[0];
    const int* src  = (const int*)d_in[1];
    const int* dst  = (const int*)d_in[2];
    const float* emb  = (const float*)d_in[3];
    const float* bias = (const float*)d_in[4];
    float* out = (float*)d_out;

    // Workspace layout (~22 MB)
    int* histD = (int*)d_ws;                          // NBUCK*NBLKP (1.6 MB)
    int* histS = histD + (size_t)NBUCK * NBLKP;       // NBUCK*NBLKP
    int* SD    = histS + (size_t)NBUCK * NBLKP;       // 800 (padded)
    int* SS    = SD + 800;
    int* baseD = SS + 800;
    int* baseS = baseD + 800;
    int* baseN = baseS + 800;                         // NN
    int* cntN  = baseN + NN;                          // NN
    unsigned int* sortedD = (unsigned int*)(cntN + NN);              // NE
    ushort4* h4 = (ushort4*)(sortedD + NE);           // NN*32 ushort4 (12.8 MB)
    unsigned short* srcfine = (unsigned short*)(h4 + (size_t)NN * 32); // NE ushort
    unsigned char* sortedS = (unsigned char*)(srcfine + NE);         // NE bytes

    hist_kernel<<<NBLKP, TPB, 0, stream>>>(src, dst, histD, histS);
    within_kernel<<<2 * NBUCK, TPB, 0, stream>>>(histD, histS, SD, SS);
    scatter_kernel<<<NBLKP, TPB, 0, stream>>>(src, dst, histD, histS, SD, SS,
                                              baseD, baseS, sortedD, sortedS);
    finehb_kernel<<<2 * NBUCK, TPB, 0, stream>>>(sortedD, sortedS, baseD, baseS, feat, emb,
                                                 baseN, cntN, srcfine, h4);
    gatherA_kernel<<<(NN * 64 + TPB - 1) / TPB, TPB, 0, stream>>>(srcfine, baseN, cntN,
                                                                  h4, bias, out);
}

// Round 13
// 81.084 us; speedup vs baseline: 8.7020x; 1.0544x over previous
//
#include <hip/hip_runtime.h>

#define NN 50000
#define NE 800000
#define DD 128
#define BSH 6
#define BSZ 64                                // nodes per bucket
#define NBUCK ((NN + BSZ - 1) / BSZ)          // 782
#define NBLK 256                              // edge-partition blocks
#define EPB ((NE + NBLK - 1) / NBLK)          // 3125
#define TPB 256

__device__ __forceinline__ unsigned short f2bf(float x) {
    unsigned u = __float_as_uint(x);
    unsigned r = u + 0x7FFF + ((u >> 16) & 1);   // round-to-nearest-even
    return (unsigned short)(r >> 16);
}
__device__ __forceinline__ float bf2f(unsigned short x) {
    return __uint_as_float((unsigned)x << 16);
}

// K1: per-block LDS histograms of dst>>6 and src>>6 (no global atomics)
__global__ void hist_kernel(const int* __restrict__ src, const int* __restrict__ dst,
                            int* __restrict__ histD, int* __restrict__ histS) {
    __shared__ int hD[NBUCK], hS[NBUCK];
    int t = threadIdx.x, blk = blockIdx.x;
    for (int b = t; b < NBUCK; b += TPB) { hD[b] = 0; hS[b] = 0; }
    __syncthreads();
    int beg = blk * EPB, end = min(beg + EPB, NE);
    for (int i = beg + t; i < end; i += TPB) {
        atomicAdd(&hD[dst[i] >> BSH], 1);
        atomicAdd(&hS[src[i] >> BSH], 1);
    }
    __syncthreads();
    for (int b = t; b < NBUCK; b += TPB) {
        histD[b * NBLK + blk] = hD[b];
        histS[b * NBLK + blk] = hS[b];
    }
}

// K2: within-bin exclusive scan over the 256 block-entries (in place) + bin total.
__global__ void within_kernel(int* __restrict__ histD, int* __restrict__ histS,
                              int* __restrict__ SD, int* __restrict__ SS) {
    __shared__ int col[NBLK];
    int t = threadIdx.x, b = blockIdx.x;
    int* hist = (b < NBUCK) ? histD : histS;
    int* S = (b < NBUCK) ? SD : SS;
    int bin = (b < NBUCK) ? b : b - NBUCK;
    int v = hist[bin * NBLK + t];
    col[t] = v;
    __syncthreads();
    for (int off = 1; off < NBLK; off <<= 1) {
        int x = (t >= off) ? col[t - off] : 0;
        __syncthreads();
        col[t] += x;
        __syncthreads();
    }
    hist[bin * NBLK + t] = col[t] - v;          // exclusive within bin
    if (t == NBLK - 1) S[bin] = col[t];         // bin total
}

// K3: scatter with fused cross-bin scan (each block scans the 782 bin totals in LDS,
// block 0 publishes baseD/baseS for finehb; cursors seeded base+within-bin offset).
__global__ void scatter_kernel(const int* __restrict__ src, const int* __restrict__ dst,
                               const int* __restrict__ offsD, const int* __restrict__ offsS,
                               const int* __restrict__ SD, const int* __restrict__ SS,
                               int* __restrict__ baseD, int* __restrict__ baseS,
                               unsigned int* __restrict__ sortedD,
                               unsigned char* __restrict__ sortedS) {
    __shared__ int curD[NBUCK], curS[NBUCK], scr[TPB];
    int t = threadIdx.x, blk = blockIdx.x;
    {   // exclusive scan of SD -> curD
        int e[4], s = 0;
        for (int k = 0; k < 4; k++) {
            int i = 4 * t + k;
            e[k] = (i < NBUCK) ? SD[i] : 0;
            s += e[k];
        }
        scr[t] = s;
        __syncthreads();
        for (int off = 1; off < TPB; off <<= 1) {
            int x = (t >= off) ? scr[t - off] : 0;
            __syncthreads();
            scr[t] += x;
            __syncthreads();
        }
        int excl = scr[t] - s;
        for (int k = 0; k < 4; k++) {
            int i = 4 * t + k;
            if (i < NBUCK) curD[i] = excl;
            excl += e[k];
        }
    }
    __syncthreads();
    {   // exclusive scan of SS -> curS
        int e[4], s = 0;
        for (int k = 0; k < 4; k++) {
            int i = 4 * t + k;
            e[k] = (i < NBUCK) ? SS[i] : 0;
            s += e[k];
        }
        scr[t] = s;
        __syncthreads();
        for (int off = 1; off < TPB; off <<= 1) {
            int x = (t >= off) ? scr[t - off] : 0;
            __syncthreads();
            scr[t] += x;
            __syncthreads();
        }
        int excl = scr[t] - s;
        for (int k = 0; k < 4; k++) {
            int i = 4 * t + k;
            if (i < NBUCK) curS[i] = excl;
            excl += e[k];
        }
    }
    __syncthreads();
    if (blk == 0) {
        for (int b = t; b < NBUCK; b += TPB) { baseD[b] = curD[b]; baseS[b] = curS[b]; }
    }
    for (int b = t; b < NBUCK; b += TPB) {
        curD[b] += offsD[b * NBLK + blk];
        curS[b] += offsS[b * NBLK + blk];
    }
    __syncthreads();
    int beg = blk * EPB, end = min(beg + EPB, NE);
    for (int i = beg + t; i < end; i += TPB) {
        int sv = src[i], dv = dst[i];
        int pD = atomicAdd(&curD[dv >> BSH], 1);
        sortedD[pD] = (unsigned)sv | ((unsigned)(dv & (BSZ - 1)) << 16);
        int pS = atomicAdd(&curS[sv >> BSH], 1);
        sortedS[pS] = (unsigned char)(sv & (BSZ - 1));
    }
}

// K4 fused: blocks [0,NBUCK) = finesort of dst-bucket; [NBUCK,2*NBUCK) = hbuild of
// src-bucket (half-wave float4 emb reads, ushort4 h writes).
__global__ void finehb_kernel(const unsigned int* __restrict__ sortedD,
                              const unsigned char* __restrict__ sortedS,
                              const int* __restrict__ baseD, const int* __restrict__ baseS,
                              const int* __restrict__ feat, const float* __restrict__ emb,
                              int* __restrict__ baseN, int* __restrict__ cntN,
                              unsigned short* __restrict__ srcfine,
                              ushort4* __restrict__ h4) {
    __shared__ int lh[BSZ], lcur[BSZ];
    int t = threadIdx.x;
    if (blockIdx.x < NBUCK) {
        int bin = blockIdx.x;
        int beg = baseD[bin];
        int end = (bin == NBUCK - 1) ? NE : baseD[bin + 1];
        if (t < BSZ) lh[t] = 0;
        __syncthreads();
        for (int i = beg + t; i < end; i += TPB) atomicAdd(&lh[sortedD[i] >> 16], 1);
        __syncthreads();
        if (t < BSZ) {                     // wave 0: shfl exclusive scan of 64
            int v = lh[t];
            int x = v;
            for (int off = 1; off < 64; off <<= 1) {
                int y = __shfl_up(x, off);
                if (t >= off) x += y;
            }
            int excl = beg + x - v;
            lcur[t] = excl;
            int n = (bin << BSH) + t;
            if (n < NN) { baseN[n] = excl; cntN[n] = v; }
        }
        __syncthreads();
        for (int i = beg + t; i < end; i += TPB) {
            unsigned e = sortedD[i];
            int pos = atomicAdd(&lcur[e >> 16], 1);
            srcfine[pos] = (unsigned short)(e & 0xFFFF);
        }
    } else {
        int bin = blockIdx.x - NBUCK;
        int beg = baseS[bin];
        int end = (bin == NBUCK - 1) ? NE : baseS[bin + 1];
        if (t < BSZ) lh[t] = 0;
        __syncthreads();
        for (int i = beg + t; i < end; i += TPB) atomicAdd(&lh[sortedS[i]], 1);
        __syncthreads();
        int w = t >> 6, lane = t & 63;
        int half = lane >> 5, sl = lane & 31;
        for (int k = 0; k < 8; k++) {
            int lo = (w << 4) + (k << 1) + half;   // wave w owns 16 consecutive nodes
            int n = (bin << BSH) + lo;
            if (n < NN) {
                float nl = rsqrtf((float)max(lh[lo], 1));
                int f = feat[n];
                float4 v = ((const float4*)(emb + (size_t)f * DD))[sl];
                h4[(size_t)n * 32 + sl] =
                    make_ushort4(f2bf(v.x * nl), f2bf(v.y * nl), f2bf(v.z * nl), f2bf(v.w * nl));
            }
        }
    }
}

// K5: one wave per dst node, two half-waves fetch different edges' 256B h-rows via
// ushort4; 8 edges/iter, 4 independent loads/lane; cross-half shfl_xor reduce.
__global__ void gatherA_kernel(const unsigned short* __restrict__ srcfine,
                               const int* __restrict__ baseN, const int* __restrict__ cntN,
                               const ushort4* __restrict__ h4, const float* __restrict__ bias,
                               float* __restrict__ out) {
    int wid = (blockIdx.x * blockDim.x + threadIdx.x) >> 6;
    int lane = threadIdx.x & 63;
    if (wid >= NN) return;
    int half = lane >> 5, sl = lane & 31;
    int cnt = cntN[wid];
    int beg = baseN[wid];
    float a0 = 0.f, a1 = 0.f, a2 = 0.f, a3 = 0.f;
    for (int b0 = 0; b0 < cnt; b0 += 64) {
        int m = min(cnt - b0, 64);
        int idx = (lane < m) ? (int)srcfine[beg + b0 + lane] : 0;
        int j = 0;
        for (; j + 7 < m; j += 8) {
            int s0 = __shfl(idx, j + half);
            int s1 = __shfl(idx, j + 2 + half);
            int s2 = __shfl(idx, j + 4 + half);
            int s3 = __shfl(idx, j + 6 + half);
            ushort4 v0 = h4[(size_t)s0 * 32 + sl];
            ushort4 v1 = h4[(size_t)s1 * 32 + sl];
            ushort4 v2 = h4[(size_t)s2 * 32 + sl];
            ushort4 v3 = h4[(size_t)s3 * 32 + sl];
            a0 += bf2f(v0.x) + bf2f(v1.x) + bf2f(v2.x) + bf2f(v3.x);
            a1 += bf2f(v0.y) + bf2f(v1.y) + bf2f(v2.y) + bf2f(v3.y);
            a2 += bf2f(v0.z) + bf2f(v1.z) + bf2f(v2.z) + bf2f(v3.z);
            a3 += bf2f(v0.w) + bf2f(v1.w) + bf2f(v2.w) + bf2f(v3.w);
        }
        for (; j + 1 < m; j += 2) {
            int s0 = __shfl(idx, j + half);
            ushort4 v0 = h4[(size_t)s0 * 32 + sl];
            a0 += bf2f(v0.x);
            a1 += bf2f(v0.y);
            a2 += bf2f(v0.z);
            a3 += bf2f(v0.w);
        }
        if (j < m) {                        // odd leftover: half 0 only
            int s0 = __shfl(idx, j);
            if (half == 0) {
                ushort4 v0 = h4[(size_t)s0 * 32 + sl];
                a0 += bf2f(v0.x);
                a1 += bf2f(v0.y);
                a2 += bf2f(v0.z);
                a3 += bf2f(v0.w);
            }
        }
    }
    a0 += __shfl_xor(a0, 32);
    a1 += __shfl_xor(a1, 32);
    a2 += __shfl_xor(a2, 32);
    a3 += __shfl_xor(a3, 32);
    if (half == 0) {
        float nr = rsqrtf((float)max(cnt, 1));
        float4 bi = ((const float4*)bias)[sl];
        ((float4*)(out + (size_t)wid * DD))[sl] =
            make_float4(a0 * nr + bi.x, a1 * nr + bi.y, a2 * nr + bi.z, a3 * nr + bi.w);
    }
}

extern "C" void kernel_launch(void* const* d_in, const int* in_sizes, int n_in,
                              void* d_out, int out_size, void* d_ws, size_t ws_size,
                              hipStream_t stream) {
    const int* feat = (const int*)d_in[0];
    const int* src  = (const int*)d_in[1];
    const int* dst  = (const int*)d_in[2];
    const float* emb  = (const float*)d_in[3];
    const float* bias = (const float*)d_in[4];
    float* out = (float*)d_out;

    // Workspace layout (~20.5 MB)
    int* histD = (int*)d_ws;                          // NBUCK*NBLK
    int* histS = histD + (size_t)NBUCK * NBLK;        // NBUCK*NBLK
    int* SD    = histS + (size_t)NBUCK * NBLK;        // 800 (padded)
    int* SS    = SD + 800;
    int* baseD = SS + 800;
    int* baseS = baseD + 800;
    int* baseN = baseS + 800;                         // NN
    int* cntN  = baseN + NN;                          // NN
    unsigned int* sortedD = (unsigned int*)(cntN + NN);              // NE
    ushort4* h4 = (ushort4*)(sortedD + NE);           // NN*32 ushort4 (12.8 MB)
    unsigned short* srcfine = (unsigned short*)(h4 + (size_t)NN * 32); // NE ushort
    unsigned char* sortedS = (unsigned char*)(srcfine + NE);         // NE bytes

    hist_kernel<<<NBLK, TPB, 0, stream>>>(src, dst, histD, histS);
    within_kernel<<<2 * NBUCK, NBLK, 0, stream>>>(histD, histS, SD, SS);
    scatter_kernel<<<NBLK, TPB, 0, stream>>>(src, dst, histD, histS, SD, SS,
                                             baseD, baseS, sortedD, sortedS);
    finehb_kernel<<<2 * NBUCK, TPB, 0, stream>>>(sortedD, sortedS, baseD, baseS, feat, emb,
                                                 baseN, cntN, srcfine, h4);
    gatherA_kernel<<<(NN * 64 + TPB - 1) / TPB, TPB, 0, stream>>>(srcfine, baseN, cntN,
                                                                  h4, bias, out);
}

// Round 14
// 79.573 us; speedup vs baseline: 8.8672x; 1.0190x over previous
//
#include <hip/hip_runtime.h>

#define NN 50000
#define NE 800000
#define DD 128
#define BSH 6
#define BSZ 64                                // nodes per bucket
#define NBUCK ((NN + BSZ - 1) / BSZ)          // 782
#define NBLK 256                              // edge-partition blocks
#define EPB ((NE + NBLK - 1) / NBLK)          // 3125
#define TPB 256

__device__ __forceinline__ unsigned short f2bf(float x) {
    unsigned u = __float_as_uint(x);
    unsigned r = u + 0x7FFF + ((u >> 16) & 1);   // round-to-nearest-even
    return (unsigned short)(r >> 16);
}
__device__ __forceinline__ float bf2f(unsigned short x) {
    return __uint_as_float((unsigned)x << 16);
}

// K1: per-block LDS histograms of dst>>6 and src>>6 (no global atomics)
__global__ void hist_kernel(const int* __restrict__ src, const int* __restrict__ dst,
                            int* __restrict__ histD, int* __restrict__ histS) {
    __shared__ int hD[NBUCK], hS[NBUCK];
    int t = threadIdx.x, blk = blockIdx.x;
    for (int b = t; b < NBUCK; b += TPB) { hD[b] = 0; hS[b] = 0; }
    __syncthreads();
    int beg = blk * EPB, end = min(beg + EPB, NE);
    for (int i = beg + t; i < end; i += TPB) {
        atomicAdd(&hD[dst[i] >> BSH], 1);
        atomicAdd(&hS[src[i] >> BSH], 1);
    }
    __syncthreads();
    for (int b = t; b < NBUCK; b += TPB) {
        histD[b * NBLK + blk] = hD[b];
        histS[b * NBLK + blk] = hS[b];
    }
}

// K2: within-bin exclusive scan via wave shfl (1 barrier) + bin total.
__global__ void within_kernel(int* __restrict__ histD, int* __restrict__ histS,
                              int* __restrict__ SD, int* __restrict__ SS) {
    __shared__ int wsum[4];
    int t = threadIdx.x, b = blockIdx.x;
    int w = t >> 6, lane = t & 63;
    int* hist = (b < NBUCK) ? histD : histS;
    int* S = (b < NBUCK) ? SD : SS;
    int bin = (b < NBUCK) ? b : b - NBUCK;
    int v = hist[bin * NBLK + t];
    int x = v;
    for (int off = 1; off < 64; off <<= 1) {
        int y = __shfl_up(x, off);
        if (lane >= off) x += y;
    }
    if (lane == 63) wsum[w] = x;
    __syncthreads();
    int base = 0;
    for (int k = 0; k < w; k++) base += wsum[k];
    int incl = base + x;
    hist[bin * NBLK + t] = incl - v;            // exclusive within bin
    if (t == NBLK - 1) S[bin] = incl;           // bin total
}

// Shfl-based block scan helper: 4 elems/thread over 256 threads (covers NBUCK=782).
// Writes exclusive prefix into cur[]. Uses 2 barriers (wsum reuse guard + publish).
__device__ __forceinline__ void blockscan4(const int* __restrict__ S, int* cur,
                                           int* wsum, int t) {
    int w = t >> 6, lane = t & 63;
    int e[4], s = 0;
    for (int k = 0; k < 4; k++) {
        int i = 4 * t + k;
        e[k] = (i < NBUCK) ? S[i] : 0;
        s += e[k];
    }
    int x = s;
    for (int off = 1; off < 64; off <<= 1) {
        int y = __shfl_up(x, off);
        if (lane >= off) x += y;
    }
    if (lane == 63) wsum[w] = x;
    __syncthreads();
    int base = 0;
    for (int k = 0; k < w; k++) base += wsum[k];
    int excl = base + x - s;
    for (int k = 0; k < 4; k++) {
        int i = 4 * t + k;
        if (i < NBUCK) cur[i] = excl;
        excl += e[k];
    }
    __syncthreads();   // wsum safe for reuse; cur[] complete
}

// K3: scatter with fused cross-bin scans (shfl-based); block 0 publishes bases.
__global__ void scatter_kernel(const int* __restrict__ src, const int* __restrict__ dst,
                               const int* __restrict__ offsD, const int* __restrict__ offsS,
                               const int* __restrict__ SD, const int* __restrict__ SS,
                               int* __restrict__ baseD, int* __restrict__ baseS,
                               unsigned int* __restrict__ sortedD,
                               unsigned char* __restrict__ sortedS) {
    __shared__ int curD[NBUCK], curS[NBUCK];
    __shared__ int wsum[4];
    int t = threadIdx.x, blk = blockIdx.x;
    blockscan4(SD, curD, wsum, t);
    blockscan4(SS, curS, wsum, t);
    if (blk == 0) {
        for (int b = t; b < NBUCK; b += TPB) { baseD[b] = curD[b]; baseS[b] = curS[b]; }
    }
    for (int b = t; b < NBUCK; b += TPB) {
        curD[b] += offsD[b * NBLK + blk];
        curS[b] += offsS[b * NBLK + blk];
    }
    __syncthreads();
    int beg = blk * EPB, end = min(beg + EPB, NE);
    for (int i = beg + t; i < end; i += TPB) {
        int sv = src[i], dv = dst[i];
        int pD = atomicAdd(&curD[dv >> BSH], 1);
        sortedD[pD] = (unsigned)sv | ((unsigned)(dv & (BSZ - 1)) << 16);
        int pS = atomicAdd(&curS[sv >> BSH], 1);
        sortedS[pS] = (unsigned char)(sv & (BSZ - 1));
    }
}

// K4 fused: blocks [0,NBUCK) = finesort of dst-bucket; [NBUCK,2*NBUCK) = hbuild of
// src-bucket (half-wave float4 emb reads, ushort4 h writes).
__global__ void finehb_kernel(const unsigned int* __restrict__ sortedD,
                              const unsigned char* __restrict__ sortedS,
                              const int* __restrict__ baseD, const int* __restrict__ baseS,
                              const int* __restrict__ feat, const float* __restrict__ emb,
                              int* __restrict__ baseN, int* __restrict__ cntN,
                              unsigned short* __restrict__ srcfine,
                              ushort4* __restrict__ h4) {
    __shared__ int lh[BSZ], lcur[BSZ];
    int t = threadIdx.x;
    if (blockIdx.x < NBUCK) {
        int bin = blockIdx.x;
        int beg = baseD[bin];
        int end = (bin == NBUCK - 1) ? NE : baseD[bin + 1];
        if (t < BSZ) lh[t] = 0;
        __syncthreads();
        for (int i = beg + t; i < end; i += TPB) atomicAdd(&lh[sortedD[i] >> 16], 1);
        __syncthreads();
        if (t < BSZ) {                     // wave 0: shfl exclusive scan of 64
            int v = lh[t];
            int x = v;
            for (int off = 1; off < 64; off <<= 1) {
                int y = __shfl_up(x, off);
                if (t >= off) x += y;
            }
            int excl = beg + x - v;
            lcur[t] = excl;
            int n = (bin << BSH) + t;
            if (n < NN) { baseN[n] = excl; cntN[n] = v; }
        }
        __syncthreads();
        for (int i = beg + t; i < end; i += TPB) {
            unsigned e = sortedD[i];
            int pos = atomicAdd(&lcur[e >> 16], 1);
            srcfine[pos] = (unsigned short)(e & 0xFFFF);
        }
    } else {
        int bin = blockIdx.x - NBUCK;
        int beg = baseS[bin];
        int end = (bin == NBUCK - 1) ? NE : baseS[bin + 1];
        if (t < BSZ) lh[t] = 0;
        __syncthreads();
        for (int i = beg + t; i < end; i += TPB) atomicAdd(&lh[sortedS[i]], 1);
        __syncthreads();
        int w = t >> 6, lane = t & 63;
        int half = lane >> 5, sl = lane & 31;
        for (int k = 0; k < 8; k++) {
            int lo = (w << 4) + (k << 1) + half;   // wave w owns 16 consecutive nodes
            int n = (bin << BSH) + lo;
            if (n < NN) {
                float nl = rsqrtf((float)max(lh[lo], 1));
                int f = feat[n];
                float4 v = ((const float4*)(emb + (size_t)f * DD))[sl];
                h4[(size_t)n * 32 + sl] =
                    make_ushort4(f2bf(v.x * nl), f2bf(v.y * nl), f2bf(v.z * nl), f2bf(v.w * nl));
            }
        }
    }
}

// K5: one wave per dst node, two half-waves fetch different edges' 256B h-rows via
// ushort4; 8 edges/iter, 4 independent loads/lane; cross-half shfl_xor reduce.
__global__ void gatherA_kernel(const unsigned short* __restrict__ srcfine,
                               const int* __restrict__ baseN, const int* __restrict__ cntN,
                               const ushort4* __restrict__ h4, const float* __restrict__ bias,
                               float* __restrict__ out) {
    int wid = (blockIdx.x * blockDim.x + threadIdx.x) >> 6;
    int lane = threadIdx.x & 63;
    if (wid >= NN) return;
    int half = lane >> 5, sl = lane & 31;
    int cnt = cntN[wid];
    int beg = baseN[wid];
    float a0 = 0.f, a1 = 0.f, a2 = 0.f, a3 = 0.f;
    for (int b0 = 0; b0 < cnt; b0 += 64) {
        int m = min(cnt - b0, 64);
        int idx = (lane < m) ? (int)srcfine[beg + b0 + lane] : 0;
        int j = 0;
        for (; j + 7 < m; j += 8) {
            int s0 = __shfl(idx, j + half);
            int s1 = __shfl(idx, j + 2 + half);
            int s2 = __shfl(idx, j + 4 + half);
            int s3 = __shfl(idx, j + 6 + half);
            ushort4 v0 = h4[(size_t)s0 * 32 + sl];
            ushort4 v1 = h4[(size_t)s1 * 32 + sl];
            ushort4 v2 = h4[(size_t)s2 * 32 + sl];
            ushort4 v3 = h4[(size_t)s3 * 32 + sl];
            a0 += bf2f(v0.x) + bf2f(v1.x) + bf2f(v2.x) + bf2f(v3.x);
            a1 += bf2f(v0.y) + bf2f(v1.y) + bf2f(v2.y) + bf2f(v3.y);
            a2 += bf2f(v0.z) + bf2f(v1.z) + bf2f(v2.z) + bf2f(v3.z);
            a3 += bf2f(v0.w) + bf2f(v1.w) + bf2f(v2.w) + bf2f(v3.w);
        }
        for (; j + 1 < m; j += 2) {
            int s0 = __shfl(idx, j + half);
            ushort4 v0 = h4[(size_t)s0 * 32 + sl];
            a0 += bf2f(v0.x);
            a1 += bf2f(v0.y);
            a2 += bf2f(v0.z);
            a3 += bf2f(v0.w);
        }
        if (j < m) {                        // odd leftover: half 0 only
            int s0 = __shfl(idx, j);
            if (half == 0) {
                ushort4 v0 = h4[(size_t)s0 * 32 + sl];
                a0 += bf2f(v0.x);
                a1 += bf2f(v0.y);
                a2 += bf2f(v0.z);
                a3 += bf2f(v0.w);
            }
        }
    }
    a0 += __shfl_xor(a0, 32);
    a1 += __shfl_xor(a1, 32);
    a2 += __shfl_xor(a2, 32);
    a3 += __shfl_xor(a3, 32);
    if (half == 0) {
        float nr = rsqrtf((float)max(cnt, 1));
        float4 bi = ((const float4*)bias)[sl];
        ((float4*)(out + (size_t)wid * DD))[sl] =
            make_float4(a0 * nr + bi.x, a1 * nr + bi.y, a2 * nr + bi.z, a3 * nr + bi.w);
    }
}

extern "C" void kernel_launch(void* const* d_in, const int* in_sizes, int n_in,
                              void* d_out, int out_size, void* d_ws, size_t ws_size,
                              hipStream_t stream) {
    const int* feat = (const int*)d_in[0];
    const int* src  = (const int*)d_in[1];
    const int* dst  = (const int*)d_in[2];
    const float* emb  = (const float*)d_in[3];
    const float* bias = (const float*)d_in[4];
    float* out = (float*)d_out;

    // Workspace layout (~20.5 MB)
    int* histD = (int*)d_ws;                          // NBUCK*NBLK
    int* histS = histD + (size_t)NBUCK * NBLK;        // NBUCK*NBLK
    int* SD    = histS + (size_t)NBUCK * NBLK;        // 800 (padded)
    int* SS    = SD + 800;
    int* baseD = SS + 800;
    int* baseS = baseD + 800;
    int* baseN = baseS + 800;                         // NN
    int* cntN  = baseN + NN;                          // NN
    unsigned int* sortedD = (unsigned int*)(cntN + NN);              // NE
    ushort4* h4 = (ushort4*)(sortedD + NE);           // NN*32 ushort4 (12.8 MB)
    unsigned short* srcfine = (unsigned short*)(h4 + (size_t)NN * 32); // NE ushort
    unsigned char* sortedS = (unsigned char*)(srcfine + NE);         // NE bytes

    hist_kernel<<<NBLK, TPB, 0, stream>>>(src, dst, histD, histS);
    within_kernel<<<2 * NBUCK, NBLK, 0, stream>>>(histD, histS, SD, SS);
    scatter_kernel<<<NBLK, TPB, 0, stream>>>(src, dst, histD, histS, SD, SS,
                                             baseD, baseS, sortedD, sortedS);
    finehb_kernel<<<2 * NBUCK, TPB, 0, stream>>>(sortedD, sortedS, baseD, baseS, feat, emb,
                                                 baseN, cntN, srcfine, h4);
    gatherA_kernel<<<(NN * 64 + TPB - 1) / TPB, TPB, 0, stream>>>(srcfine, baseN, cntN,
                                                                  h4, bias, out);
}

// Round 15
// 74.895 us; speedup vs baseline: 9.4211x; 1.0625x over previous
//
#include <hip/hip_runtime.h>

#define NN 50000
#define NE 800000
#define DD 128
#define BSH 6
#define BSZ 64                                // nodes per bucket
#define NBUCK ((NN + BSZ - 1) / BSZ)          // 782
#define NBLK 256                              // edge-partition blocks
#define EPB ((NE + NBLK - 1) / NBLK)          // 3125
#define TPB_H 1024                            // hist block
#define TPB_SC 512                            // scatter block
#define TPB_F 512                             // finehb block

__device__ __forceinline__ unsigned short f2bf(float x) {
    unsigned u = __float_as_uint(x);
    unsigned r = u + 0x7FFF + ((u >> 16) & 1);   // round-to-nearest-even
    return (unsigned short)(r >> 16);
}
__device__ __forceinline__ float bf2f(unsigned short x) {
    return __uint_as_float((unsigned)x << 16);
}

// K1: per-block LDS histograms of dst>>6 and src>>6 (no global atomics)
__global__ void __launch_bounds__(TPB_H) hist_kernel(
        const int* __restrict__ src, const int* __restrict__ dst,
        int* __restrict__ histD, int* __restrict__ histS) {
    __shared__ int hD[NBUCK], hS[NBUCK];
    int t = threadIdx.x, blk = blockIdx.x;
    for (int b = t; b < NBUCK; b += TPB_H) { hD[b] = 0; hS[b] = 0; }
    __syncthreads();
    int beg = blk * EPB, end = min(beg + EPB, NE);
    for (int i = beg + t; i < end; i += TPB_H) {
        atomicAdd(&hD[dst[i] >> BSH], 1);
        atomicAdd(&hS[src[i] >> BSH], 1);
    }
    __syncthreads();
    for (int b = t; b < NBUCK; b += TPB_H) {
        histD[b * NBLK + blk] = hD[b];
        histS[b * NBLK + blk] = hS[b];
    }
}

// K2: within-bin exclusive scan via wave shfl (1 barrier) + bin total.
__global__ void within_kernel(int* __restrict__ histD, int* __restrict__ histS,
                              int* __restrict__ SD, int* __restrict__ SS) {
    __shared__ int wsum[4];
    int t = threadIdx.x, b = blockIdx.x;
    int w = t >> 6, lane = t & 63;
    int* hist = (b < NBUCK) ? histD : histS;
    int* S = (b < NBUCK) ? SD : SS;
    int bin = (b < NBUCK) ? b : b - NBUCK;
    int v = hist[bin * NBLK + t];
    int x = v;
    for (int off = 1; off < 64; off <<= 1) {
        int y = __shfl_up(x, off);
        if (lane >= off) x += y;
    }
    if (lane == 63) wsum[w] = x;
    __syncthreads();
    int base = 0;
    for (int k = 0; k < w; k++) base += wsum[k];
    int incl = base + x;
    hist[bin * NBLK + t] = incl - v;            // exclusive within bin
    if (t == NBLK - 1) S[bin] = incl;           // bin total
}

// Shfl-based block scan: 2 elems/thread over 512 threads (covers NBUCK=782).
__device__ __forceinline__ void blockscan2(const int* __restrict__ S, int* cur,
                                           int* wsum, int t) {
    int w = t >> 6, lane = t & 63;
    int i0 = 2 * t, i1 = 2 * t + 1;
    int e0 = (i0 < NBUCK) ? S[i0] : 0;
    int e1 = (i1 < NBUCK) ? S[i1] : 0;
    int s = e0 + e1;
    int x = s;
    for (int off = 1; off < 64; off <<= 1) {
        int y = __shfl_up(x, off);
        if (lane >= off) x += y;
    }
    if (lane == 63) wsum[w] = x;
    __syncthreads();
    int base = 0;
    for (int k = 0; k < w; k++) base += wsum[k];
    int excl = base + x - s;
    if (i0 < NBUCK) cur[i0] = excl;
    if (i1 < NBUCK) cur[i1] = excl + e0;
    __syncthreads();   // wsum safe for reuse; cur[] complete
}

// K3: scatter with fused cross-bin scans (shfl-based); block 0 publishes bases.
__global__ void __launch_bounds__(TPB_SC) scatter_kernel(
        const int* __restrict__ src, const int* __restrict__ dst,
        const int* __restrict__ offsD, const int* __restrict__ offsS,
        const int* __restrict__ SD, const int* __restrict__ SS,
        int* __restrict__ baseD, int* __restrict__ baseS,
        unsigned int* __restrict__ sortedD, unsigned char* __restrict__ sortedS) {
    __shared__ int curD[NBUCK], curS[NBUCK];
    __shared__ int wsum[8];
    int t = threadIdx.x, blk = blockIdx.x;
    blockscan2(SD, curD, wsum, t);
    blockscan2(SS, curS, wsum, t);
    if (blk == 0) {
        for (int b = t; b < NBUCK; b += TPB_SC) { baseD[b] = curD[b]; baseS[b] = curS[b]; }
    }
    for (int b = t; b < NBUCK; b += TPB_SC) {
        curD[b] += offsD[b * NBLK + blk];
        curS[b] += offsS[b * NBLK + blk];
    }
    __syncthreads();
    int beg = blk * EPB, end = min(beg + EPB, NE);
    for (int i = beg + t; i < end; i += TPB_SC) {
        int sv = src[i], dv = dst[i];
        int pD = atomicAdd(&curD[dv >> BSH], 1);
        sortedD[pD] = (unsigned)sv | ((unsigned)(dv & (BSZ - 1)) << 16);
        int pS = atomicAdd(&curS[sv >> BSH], 1);
        sortedS[pS] = (unsigned char)(sv & (BSZ - 1));
    }
}

// K4 fused: blocks [0,NBUCK) = finesort of dst-bucket; [NBUCK,2*NBUCK) = hbuild of
// src-bucket (half-wave float4 emb reads, ushort4 h writes). 8 waves/block.
__global__ void __launch_bounds__(TPB_F) finehb_kernel(
        const unsigned int* __restrict__ sortedD, const unsigned char* __restrict__ sortedS,
        const int* __restrict__ baseD, const int* __restrict__ baseS,
        const int* __restrict__ feat, const float* __restrict__ emb,
        int* __restrict__ baseN, int* __restrict__ cntN,
        unsigned short* __restrict__ srcfine, ushort4* __restrict__ h4) {
    __shared__ int lh[BSZ], lcur[BSZ];
    int t = threadIdx.x;
    if (blockIdx.x < NBUCK) {
        int bin = blockIdx.x;
        int beg = baseD[bin];
        int end = (bin == NBUCK - 1) ? NE : baseD[bin + 1];
        if (t < BSZ) lh[t] = 0;
        __syncthreads();
        for (int i = beg + t; i < end; i += TPB_F) atomicAdd(&lh[sortedD[i] >> 16], 1);
        __syncthreads();
        if (t < BSZ) {                     // wave 0: shfl exclusive scan of 64
            int v = lh[t];
            int x = v;
            for (int off = 1; off < 64; off <<= 1) {
                int y = __shfl_up(x, off);
                if (t >= off) x += y;
            }
            int excl = beg + x - v;
            lcur[t] = excl;
            int n = (bin << BSH) + t;
            if (n < NN) { baseN[n] = excl; cntN[n] = v; }
        }
        __syncthreads();
        for (int i = beg + t; i < end; i += TPB_F) {
            unsigned e = sortedD[i];
            int pos = atomicAdd(&lcur[e >> 16], 1);
            srcfine[pos] = (unsigned short)(e & 0xFFFF);
        }
    } else {
        int bin = blockIdx.x - NBUCK;
        int beg = baseS[bin];
        int end = (bin == NBUCK - 1) ? NE : baseS[bin + 1];
        if (t < BSZ) lh[t] = 0;
        __syncthreads();
        for (int i = beg + t; i < end; i += TPB_F) atomicAdd(&lh[sortedS[i]], 1);
        __syncthreads();
        int w = t >> 6, lane = t & 63;       // 8 waves x 8 nodes each
        int half = lane >> 5, sl = lane & 31;
        for (int k = 0; k < 4; k++) {
            int lo = (w << 3) + (k << 1) + half;
            int n = (bin << BSH) + lo;
            if (n < NN) {
                float nl = rsqrtf((float)max(lh[lo], 1));
                int f = feat[n];
                float4 v = ((const float4*)(emb + (size_t)f * DD))[sl];
                h4[(size_t)n * 32 + sl] =
                    make_ushort4(f2bf(v.x * nl), f2bf(v.y * nl), f2bf(v.z * nl), f2bf(v.w * nl));
            }
        }
    }
}

// K5: one wave per dst node, two half-waves fetch different edges' 256B h-rows via
// ushort4; 8 edges/iter, 4 independent loads/lane; cross-half shfl_xor reduce.
__global__ void gatherA_kernel(const unsigned short* __restrict__ srcfine,
                               const int* __restrict__ baseN, const int* __restrict__ cntN,
                               const ushort4* __restrict__ h4, const float* __restrict__ bias,
                               float* __restrict__ out) {
    int wid = (blockIdx.x * blockDim.x + threadIdx.x) >> 6;
    int lane = threadIdx.x & 63;
    if (wid >= NN) return;
    int half = lane >> 5, sl = lane & 31;
    int cnt = cntN[wid];
    int beg = baseN[wid];
    float a0 = 0.f, a1 = 0.f, a2 = 0.f, a3 = 0.f;
    for (int b0 = 0; b0 < cnt; b0 += 64) {
        int m = min(cnt - b0, 64);
        int idx = (lane < m) ? (int)srcfine[beg + b0 + lane] : 0;
        int j = 0;
        for (; j + 7 < m; j += 8) {
            int s0 = __shfl(idx, j + half);
            int s1 = __shfl(idx, j + 2 + half);
            int s2 = __shfl(idx, j + 4 + half);
            int s3 = __shfl(idx, j + 6 + half);
            ushort4 v0 = h4[(size_t)s0 * 32 + sl];
            ushort4 v1 = h4[(size_t)s1 * 32 + sl];
            ushort4 v2 = h4[(size_t)s2 * 32 + sl];
            ushort4 v3 = h4[(size_t)s3 * 32 + sl];
            a0 += bf2f(v0.x) + bf2f(v1.x) + bf2f(v2.x) + bf2f(v3.x);
            a1 += bf2f(v0.y) + bf2f(v1.y) + bf2f(v2.y) + bf2f(v3.y);
            a2 += bf2f(v0.z) + bf2f(v1.z) + bf2f(v2.z) + bf2f(v3.z);
            a3 += bf2f(v0.w) + bf2f(v1.w) + bf2f(v2.w) + bf2f(v3.w);
        }
        for (; j + 1 < m; j += 2) {
            int s0 = __shfl(idx, j + half);
            ushort4 v0 = h4[(size_t)s0 * 32 + sl];
            a0 += bf2f(v0.x);
            a1 += bf2f(v0.y);
            a2 += bf2f(v0.z);
            a3 += bf2f(v0.w);
        }
        if (j < m) {                        // odd leftover: half 0 only
            int s0 = __shfl(idx, j);
            if (half == 0) {
                ushort4 v0 = h4[(size_t)s0 * 32 + sl];
                a0 += bf2f(v0.x);
                a1 += bf2f(v0.y);
                a2 += bf2f(v0.z);
                a3 += bf2f(v0.w);
            }
        }
    }
    a0 += __shfl_xor(a0, 32);
    a1 += __shfl_xor(a1, 32);
    a2 += __shfl_xor(a2, 32);
    a3 += __shfl_xor(a3, 32);
    if (half == 0) {
        float nr = rsqrtf((float)max(cnt, 1));
        float4 bi = ((const float4*)bias)[sl];
        ((float4*)(out + (size_t)wid * DD))[sl] =
            make_float4(a0 * nr + bi.x, a1 * nr + bi.y, a2 * nr + bi.z, a3 * nr + bi.w);
    }
}

extern "C" void kernel_launch(void* const* d_in, const int* in_sizes, int n_in,
                              void* d_out, int out_size, void* d_ws, size_t ws_size,
                              hipStream_t stream) {
    const int* feat = (const int*)d_in[0];
    const int* src  = (const int*)d_in[1];
    const int* dst  = (const int*)d_in[2];
    const float* emb  = (const float*)d_in[3];
    const float* bias = (const float*)d_in[4];
    float* out = (float*)d_out;

    // Workspace layout (~20.5 MB)
    int* histD = (int*)d_ws;                          // NBUCK*NBLK
    int* histS = histD + (size_t)NBUCK * NBLK;        // NBUCK*NBLK
    int* SD    = histS + (size_t)NBUCK * NBLK;        // 800 (padded)
    int* SS    = SD + 800;
    int* baseD = SS + 800;
    int* baseS = baseD + 800;
    int* baseN = baseS + 800;                         // NN
    int* cntN  = baseN + NN;                          // NN
    unsigned int* sortedD = (unsigned int*)(cntN + NN);              // NE
    ushort4* h4 = (ushort4*)(sortedD + NE);           // NN*32 ushort4 (12.8 MB)
    unsigned short* srcfine = (unsigned short*)(h4 + (size_t)NN * 32); // NE ushort
    unsigned char* sortedS = (unsigned char*)(srcfine + NE);         // NE bytes

    hist_kernel<<<NBLK, TPB_H, 0, stream>>>(src, dst, histD, histS);
    within_kernel<<<2 * NBUCK, NBLK, 0, stream>>>(histD, histS, SD, SS);
    scatter_kernel<<<NBLK, TPB_SC, 0, stream>>>(src, dst, histD, histS, SD, SS,
                                                baseD, baseS, sortedD, sortedS);
    finehb_kernel<<<2 * NBUCK, TPB_F, 0, stream>>>(sortedD, sortedS, baseD, baseS, feat, emb,
                                                   baseN, cntN, srcfine, h4);
    gatherA_kernel<<<(NN * 64 + 255) / 256, 256, 0, stream>>>(srcfine, baseN, cntN,
                                                              h4, bias, out);
}